// Round 1
// baseline (664.997 us; speedup 1.0000x reference)
//
#include <hip/hip_runtime.h>

// Complex MHA, B=4 S=1024 E=1024 H=16 DH=64.
// Pipeline: pack(fp32->fp16, K-concat complex trick) -> GEMM1 (QKV proj, scatter
// epilogue into QC/KCr/KCi/VCT) -> flash-style complex attention -> GEMM2 (out proj).
// d_out assumed float32 real-part (out_size==4M); complex-interleaved handled if 8M.

typedef _Float16 f16;
typedef _Float16 f16x8 __attribute__((ext_vector_type(8)));
typedef _Float16 f16x4 __attribute__((ext_vector_type(4)));
typedef float f32x4 __attribute__((ext_vector_type(4)));

#define MFMA16(a, b, c) __builtin_amdgcn_mfma_f32_16x16x32_f16(a, b, c, 0, 0, 0)

__device__ inline void load_lds16(const void* g, void* l) {
  __builtin_amdgcn_global_load_lds(
      (const __attribute__((address_space(1))) unsigned int*)g,
      (__attribute__((address_space(3))) unsigned int*)l, 16, 0, 0);
}

__device__ inline float rmax16(float v) {
#pragma unroll
  for (int m = 1; m < 16; m <<= 1) v = fmaxf(v, __shfl_xor(v, m));
  return v;
}
__device__ inline float rsum16(float v) {
#pragma unroll
  for (int m = 1; m < 16; m <<= 1) v += __shfl_xor(v, m);
  return v;
}

// ---------------- pack kernels (fp32 -> fp16, concat layouts) ----------------

// XC[4096][2048] = [x_real | x_imag]
__global__ void pack_x_kernel(const float* __restrict__ xr, const float* __restrict__ xi,
                              f16* __restrict__ XC) {
  int i = blockIdx.x * 256 + threadIdx.x;
  if (i >= (4096 * 2048 / 4)) return;
  int idx = i * 4;
  int m = idx >> 11, k = idx & 2047;
  const float* src = (k < 1024) ? (xr + (size_t)m * 1024 + k) : (xi + (size_t)m * 1024 + k - 1024);
  float4 v = *(const float4*)src;
  f16x4 o = {(f16)v.x, (f16)v.y, (f16)v.z, (f16)v.w};
  *(f16x4*)(XC + idx) = o;
}

// WQKV[6144][2048]: rows 0..3071 (real out): [Wr | -Wi]; rows 3072..6143 (imag out): [Wi | Wr]
__global__ void pack_wqkv_kernel(const float* __restrict__ wr, const float* __restrict__ wi,
                                 f16* __restrict__ W) {
  int i = blockIdx.x * 256 + threadIdx.x;
  if (i >= (6144 * 2048 / 4)) return;
  int idx = i * 4;
  int n = idx >> 11, k = idx & 2047;
  const float* base;
  float sgn = 1.f;
  if (n < 3072) {
    if (k < 1024) base = wr + (size_t)n * 1024 + k;
    else { base = wi + (size_t)n * 1024 + k - 1024; sgn = -1.f; }
  } else {
    int n2 = n - 3072;
    if (k < 1024) base = wi + (size_t)n2 * 1024 + k;
    else base = wr + (size_t)n2 * 1024 + k - 1024;
  }
  float4 v = *(const float4*)base;
  f16x4 o = {(f16)(sgn * v.x), (f16)(sgn * v.y), (f16)(sgn * v.z), (f16)(sgn * v.w)};
  *(f16x4*)(W + idx) = o;
}

// WOUT[2048][2048]: rows 0..1023 (real out): [Wor | -Woi]; rows 1024..2047 (imag): [Woi | Wor]
__global__ void pack_wout_kernel(const float* __restrict__ wor, const float* __restrict__ woi,
                                 f16* __restrict__ W) {
  int i = blockIdx.x * 256 + threadIdx.x;
  if (i >= (2048 * 2048 / 4)) return;
  int idx = i * 4;
  int n = idx >> 11, k = idx & 2047;
  const float* base;
  float sgn = 1.f;
  if (n < 1024) {
    if (k < 1024) base = wor + (size_t)n * 1024 + k;
    else { base = woi + (size_t)n * 1024 + k - 1024; sgn = -1.f; }
  } else {
    int n2 = n - 1024;
    if (k < 1024) base = woi + (size_t)n2 * 1024 + k;
    else base = wor + (size_t)n2 * 1024 + k - 1024;
  }
  float4 v = *(const float4*)base;
  f16x4 o = {(f16)(sgn * v.x), (f16)(sgn * v.y), (f16)(sgn * v.z), (f16)(sgn * v.w)};
  *(f16x4*)(W + idx) = o;
}

// ---------------- GEMM: C[M,N] = A[M,K=2048] * B[N,K=2048]^T -------------------
// 128x128 tile, BK=64, 4 waves (2x2, each 64x64). global_load_lds w/ source-side
// XOR swizzle (chunk ^= row&7 within 128B rows), swizzled ds_read_b128.

struct GemmParams {
  f16 *QC, *KCr, *KCi, *VCT;           // mode 0 scatter targets
  const float *bpr, *bpi;              // packed bias (real/imag), len 3072 each
  float* out;                          // mode 1
  const float *bor, *boi;              // out bias, len 1024 each
  int out_complex;
};

template <int MODE>
__global__ __launch_bounds__(256) void gemm_kernel(const f16* __restrict__ A,
                                                   const f16* __restrict__ B,
                                                   GemmParams p) {
  const int K = 2048;
  __shared__ alignas(16) f16 sA[128 * 64];
  __shared__ alignas(16) f16 sB[128 * 64];
  const int tid = threadIdx.x;
  const int w = tid >> 6, l = tid & 63;
  const int lr = l & 15, lk = l >> 4;
  const int tm0 = blockIdx.y * 128, tn0 = blockIdx.x * 128;
  const int wm = (w >> 1) * 64, wn = (w & 1) * 64;

  f32x4 acc[4][4] = {};

  for (int k0 = 0; k0 < K; k0 += 64) {
#pragma unroll
    for (int i = 0; i < 4; ++i) {
      int slot = i * 256 + tid;
      int row = slot >> 3;
      int cg = (slot & 7) ^ (row & 7);
      load_lds16(A + (size_t)(tm0 + row) * K + k0 + cg * 8, &sA[(size_t)(i * 256 + (w << 6)) * 8]);
      load_lds16(B + (size_t)(tn0 + row) * K + k0 + cg * 8, &sB[(size_t)(i * 256 + (w << 6)) * 8]);
    }
    __syncthreads();
#pragma unroll
    for (int kk = 0; kk < 2; ++kk) {
      f16x8 af[4], bf[4];
#pragma unroll
      for (int t = 0; t < 4; ++t) {
        int rowA = wm + t * 16 + lr;
        af[t] = *(const f16x8*)&sA[rowA * 64 + ((kk * 4 + lk) ^ (rowA & 7)) * 8];
        int rowB = wn + t * 16 + lr;
        bf[t] = *(const f16x8*)&sB[rowB * 64 + ((kk * 4 + lk) ^ (rowB & 7)) * 8];
      }
#pragma unroll
      for (int mt = 0; mt < 4; ++mt)
#pragma unroll
        for (int nt = 0; nt < 4; ++nt) acc[mt][nt] = MFMA16(af[mt], bf[nt], acc[mt][nt]);
    }
    __syncthreads();
  }

  // epilogue: C/D layout col=lane&15, row=(lane>>4)*4+reg
#pragma unroll
  for (int mt = 0; mt < 4; ++mt)
#pragma unroll
    for (int nt = 0; nt < 4; ++nt)
#pragma unroll
      for (int r = 0; r < 4; ++r) {
        int m = tm0 + wm + mt * 16 + lk * 4 + r;
        int n = tn0 + wn + nt * 16 + lr;
        float val = acc[mt][nt][r];
        if constexpr (MODE == 0) {
          bool im = n >= 3072;
          int nn = im ? n - 3072 : n;
          float v2 = val + (im ? p.bpi[nn] : p.bpr[nn]);
          int part = nn >> 10;
          int e = nn & 1023, h = e >> 6, d = e & 63;
          int bb = m >> 10, s = m & 1023;
          size_t bh = (size_t)bb * 16 + h;
          if (part == 0) {
            // q, scaled by 1/sqrt(DH)=1/8. QC = [Qr | Qi]
            p.QC[(bh * 1024 + s) * 128 + (im ? 64 : 0) + d] = (f16)(v2 * 0.125f);
          } else if (part == 1) {
            // KCr = [Kr | -Ki], KCi = [Ki | Kr]
            size_t o = (bh * 1024 + s) * 128;
            if (!im) { p.KCr[o + d] = (f16)v2; p.KCi[o + 64 + d] = (f16)v2; }
            else     { p.KCr[o + 64 + d] = (f16)(-v2); p.KCi[o + d] = (f16)v2; }
          } else {
            // V transposed per head: VCT[bh][feat(0..127)][s], feat = (im?64:0)+d
            p.VCT[(bh * 128 + (im ? 64 : 0) + d) * 1024 + s] = (f16)v2;
          }
        } else {
          if (n < 1024) {
            float v2 = val + p.bor[n];
            if (p.out_complex) p.out[((size_t)m * 1024 + n) * 2] = v2;
            else p.out[(size_t)m * 1024 + n] = v2;
          } else {
            if (p.out_complex) p.out[((size_t)m * 1024 + n - 1024) * 2 + 1] = val + p.boi[n - 1024];
          }
        }
      }
}

// ---------------- flash-style complex attention -------------------------------
// grid = B*H*16 blocks; block = 4 waves; wave handles 16 q-rows; KBLK=32.

__global__ __launch_bounds__(256) void attn_kernel(const f16* __restrict__ QC,
                                                   const f16* __restrict__ KCr,
                                                   const f16* __restrict__ KCi,
                                                   const f16* __restrict__ VCT,
                                                   f16* __restrict__ OC) {
  __shared__ alignas(16) f16 smP[4][2][16 * 32];
  const int tid = threadIdx.x;
  const int w = tid >> 6, l = tid & 63;
  const int lr = l & 15, lk = l >> 4;
  const int bid = blockIdx.x;
  const int qt = bid & 15;
  const int bh = bid >> 4;
  const int q0 = qt * 64 + w * 16;
  const f16* Qb = QC + (size_t)bh * 1024 * 128;
  const f16* Krb = KCr + (size_t)bh * 1024 * 128;
  const f16* Kib = KCi + (size_t)bh * 1024 * 128;
  const f16* Vb = VCT + (size_t)bh * 128 * 1024;

  f16x8 qf[4];
#pragma unroll
  for (int c = 0; c < 4; ++c)
    qf[c] = *(const f16x8*)&Qb[(size_t)(q0 + lr) * 128 + c * 32 + lk * 8];

  f32x4 accR[8] = {};  // Pr @ [Vr|Vi]
  f32x4 accI[8] = {};  // Pi @ [Vr|Vi]
  float m_r[4], l_r[4], m_i[4], l_i[4];
#pragma unroll
  for (int r = 0; r < 4; ++r) { m_r[r] = -1e30f; l_r[r] = 0.f; m_i[r] = -1e30f; l_i[r] = 0.f; }

  for (int k0 = 0; k0 < 1024; k0 += 32) {
    f32x4 sr[2] = {}, si[2] = {};
#pragma unroll
    for (int c = 0; c < 4; ++c) {
      f16x8 kr0 = *(const f16x8*)&Krb[(size_t)(k0 + lr) * 128 + c * 32 + lk * 8];
      f16x8 kr1 = *(const f16x8*)&Krb[(size_t)(k0 + 16 + lr) * 128 + c * 32 + lk * 8];
      f16x8 ki0 = *(const f16x8*)&Kib[(size_t)(k0 + lr) * 128 + c * 32 + lk * 8];
      f16x8 ki1 = *(const f16x8*)&Kib[(size_t)(k0 + 16 + lr) * 128 + c * 32 + lk * 8];
      sr[0] = MFMA16(qf[c], kr0, sr[0]);
      sr[1] = MFMA16(qf[c], kr1, sr[1]);
      si[0] = MFMA16(qf[c], ki0, si[0]);
      si[1] = MFMA16(qf[c], ki1, si[1]);
    }
    // online softmax, real part
#pragma unroll
    for (int r = 0; r < 4; ++r) {
      float vm = rmax16(fmaxf(sr[0][r], sr[1][r]));
      float nm = fmaxf(m_r[r], vm);
      float sc = __expf(m_r[r] - nm);
      float p0 = __expf(sr[0][r] - nm);
      float p1 = __expf(sr[1][r] - nm);
      float rs = rsum16(p0 + p1);
      l_r[r] = l_r[r] * sc + rs;
      m_r[r] = nm;
#pragma unroll
      for (int t = 0; t < 8; ++t) accR[t][r] *= sc;
      smP[w][0][(lk * 4 + r) * 32 + lr] = (f16)p0;
      smP[w][0][(lk * 4 + r) * 32 + 16 + lr] = (f16)p1;
    }
    // online softmax, imag part
#pragma unroll
    for (int r = 0; r < 4; ++r) {
      float vm = rmax16(fmaxf(si[0][r], si[1][r]));
      float nm = fmaxf(m_i[r], vm);
      float sc = __expf(m_i[r] - nm);
      float p0 = __expf(si[0][r] - nm);
      float p1 = __expf(si[1][r] - nm);
      float rs = rsum16(p0 + p1);
      l_i[r] = l_i[r] * sc + rs;
      m_i[r] = nm;
#pragma unroll
      for (int t = 0; t < 8; ++t) accI[t][r] *= sc;
      smP[w][1][(lk * 4 + r) * 32 + lr] = (f16)p0;
      smP[w][1][(lk * 4 + r) * 32 + 16 + lr] = (f16)p1;
    }
    // P fragments (A-operand layout) from LDS
    f16x8 pr = *(const f16x8*)&smP[w][0][lr * 32 + lk * 8];
    f16x8 pi = *(const f16x8*)&smP[w][1][lr * 32 + lk * 8];
#pragma unroll
    for (int f = 0; f < 8; ++f) {
      f16x8 vf = *(const f16x8*)&Vb[(size_t)(f * 16 + lr) * 1024 + k0 + lk * 8];
      accR[f] = MFMA16(pr, vf, accR[f]);
      accI[f] = MFMA16(pi, vf, accI[f]);
    }
  }

  const int bb = bh >> 4, h = bh & 15;
#pragma unroll
  for (int t = 0; t < 4; ++t)
#pragma unroll
    for (int r = 0; r < 4; ++r) {
      int qrow = q0 + lk * 4 + r;
      size_t m = (size_t)bb * 1024 + qrow;
      int d = t * 16 + lr;
      float ilr = 1.f / l_r[r], ili = 1.f / l_i[r];
      float orv = accR[t][r] * ilr - accI[t + 4][r] * ili;
      float oiv = accR[t + 4][r] * ilr + accI[t][r] * ili;
      OC[m * 2048 + h * 64 + d] = (f16)orv;
      OC[m * 2048 + 1024 + h * 64 + d] = (f16)oiv;
    }
}

// ---------------- launcher ----------------------------------------------------

extern "C" void kernel_launch(void* const* d_in, const int* in_sizes, int n_in,
                              void* d_out, int out_size, void* d_ws, size_t ws_size,
                              hipStream_t stream) {
  const float* xr = (const float*)d_in[0];
  const float* xi = (const float*)d_in[1];
  const float* wpr = (const float*)d_in[2];
  const float* wpi = (const float*)d_in[3];
  const float* bpr = (const float*)d_in[4];
  const float* bpi = (const float*)d_in[5];
  const float* wor = (const float*)d_in[6];
  const float* woi = (const float*)d_in[7];
  const float* bor = (const float*)d_in[8];
  const float* boi = (const float*)d_in[9];

  f16* ws = (f16*)d_ws;
  f16* XC = ws;                       // 4096*2048
  f16* WQKV = XC + 8388608;           // 6144*2048
  f16* QC = WQKV + 12582912;          // 64*1024*128
  f16* KCr = QC + 8388608;
  f16* KCi = KCr + 8388608;
  f16* VCT = KCi + 8388608;           // 64*128*1024
  f16* OC = VCT + 8388608;            // 4096*2048
  f16* WOUT = OC + 8388608;           // 2048*2048

  pack_x_kernel<<<8192, 256, 0, stream>>>(xr, xi, XC);
  pack_wqkv_kernel<<<12288, 256, 0, stream>>>(wpr, wpi, WQKV);
  pack_wout_kernel<<<4096, 256, 0, stream>>>(wor, woi, WOUT);

  GemmParams p1 = {};
  p1.QC = QC; p1.KCr = KCr; p1.KCi = KCi; p1.VCT = VCT;
  p1.bpr = bpr; p1.bpi = bpi;
  gemm_kernel<0><<<dim3(48, 32), 256, 0, stream>>>(XC, WQKV, p1);

  attn_kernel<<<1024, 256, 0, stream>>>(QC, KCr, KCi, VCT, OC);

  GemmParams p2 = {};
  p2.out = (float*)d_out; p2.bor = bor; p2.boi = boi;
  p2.out_complex = (out_size == 8388608) ? 1 : 0;
  int ntilesN = p2.out_complex ? 16 : 8;
  gemm_kernel<1><<<dim3(ntilesN, 32), 256, 0, stream>>>(OC, WOUT, p2);
}

// Round 2
// 525.278 us; speedup vs baseline: 1.2660x; 1.2660x over previous
//
#include <hip/hip_runtime.h>

// Complex MHA, B=4 S=1024 E=1024 H=16 DH=64.
// Pipeline: pack(fp32->fp16, K-concat complex trick) -> GEMM1 (QKV proj, scatter
// epilogue into QC/KCr/KCi/VCT) -> flash-style complex attention (LDS-staged K/V,
// XOR-swizzled, defer-max) -> GEMM2 (out proj).

typedef _Float16 f16;
typedef _Float16 f16x8 __attribute__((ext_vector_type(8)));
typedef _Float16 f16x4 __attribute__((ext_vector_type(4)));
typedef float f32x4 __attribute__((ext_vector_type(4)));

#define MFMA16(a, b, c) __builtin_amdgcn_mfma_f32_16x16x32_f16(a, b, c, 0, 0, 0)

__device__ inline void load_lds16(const void* g, void* l) {
  __builtin_amdgcn_global_load_lds(
      (const __attribute__((address_space(1))) unsigned int*)g,
      (__attribute__((address_space(3))) unsigned int*)l, 16, 0, 0);
}

__device__ inline float rmax16(float v) {
#pragma unroll
  for (int m = 1; m < 16; m <<= 1) v = fmaxf(v, __shfl_xor(v, m));
  return v;
}
__device__ inline float rsum16(float v) {
#pragma unroll
  for (int m = 1; m < 16; m <<= 1) v += __shfl_xor(v, m);
  return v;
}

// ---------------- pack kernels (fp32 -> fp16, concat layouts) ----------------

__global__ void pack_x_kernel(const float* __restrict__ xr, const float* __restrict__ xi,
                              f16* __restrict__ XC) {
  int i = blockIdx.x * 256 + threadIdx.x;
  if (i >= (4096 * 2048 / 4)) return;
  int idx = i * 4;
  int m = idx >> 11, k = idx & 2047;
  const float* src = (k < 1024) ? (xr + (size_t)m * 1024 + k) : (xi + (size_t)m * 1024 + k - 1024);
  float4 v = *(const float4*)src;
  f16x4 o = {(f16)v.x, (f16)v.y, (f16)v.z, (f16)v.w};
  *(f16x4*)(XC + idx) = o;
}

__global__ void pack_wqkv_kernel(const float* __restrict__ wr, const float* __restrict__ wi,
                                 f16* __restrict__ W) {
  int i = blockIdx.x * 256 + threadIdx.x;
  if (i >= (6144 * 2048 / 4)) return;
  int idx = i * 4;
  int n = idx >> 11, k = idx & 2047;
  const float* base;
  float sgn = 1.f;
  if (n < 3072) {
    if (k < 1024) base = wr + (size_t)n * 1024 + k;
    else { base = wi + (size_t)n * 1024 + k - 1024; sgn = -1.f; }
  } else {
    int n2 = n - 3072;
    if (k < 1024) base = wi + (size_t)n2 * 1024 + k;
    else base = wr + (size_t)n2 * 1024 + k - 1024;
  }
  float4 v = *(const float4*)base;
  f16x4 o = {(f16)(sgn * v.x), (f16)(sgn * v.y), (f16)(sgn * v.z), (f16)(sgn * v.w)};
  *(f16x4*)(W + idx) = o;
}

__global__ void pack_wout_kernel(const float* __restrict__ wor, const float* __restrict__ woi,
                                 f16* __restrict__ W) {
  int i = blockIdx.x * 256 + threadIdx.x;
  if (i >= (2048 * 2048 / 4)) return;
  int idx = i * 4;
  int n = idx >> 11, k = idx & 2047;
  const float* base;
  float sgn = 1.f;
  if (n < 1024) {
    if (k < 1024) base = wor + (size_t)n * 1024 + k;
    else { base = woi + (size_t)n * 1024 + k - 1024; sgn = -1.f; }
  } else {
    int n2 = n - 1024;
    if (k < 1024) base = woi + (size_t)n2 * 1024 + k;
    else base = wor + (size_t)n2 * 1024 + k - 1024;
  }
  float4 v = *(const float4*)base;
  f16x4 o = {(f16)(sgn * v.x), (f16)(sgn * v.y), (f16)(sgn * v.z), (f16)(sgn * v.w)};
  *(f16x4*)(W + idx) = o;
}

// ---------------- GEMM: C[M,N] = A[M,K=2048] * B[N,K=2048]^T -------------------

struct GemmParams {
  f16 *QC, *KCr, *KCi, *VCT;
  const float *bpr, *bpi;
  float* out;
  const float *bor, *boi;
  int out_complex;
};

template <int MODE>
__global__ __launch_bounds__(256) void gemm_kernel(const f16* __restrict__ A,
                                                   const f16* __restrict__ B,
                                                   GemmParams p) {
  const int K = 2048;
  __shared__ alignas(16) f16 sA[128 * 64];
  __shared__ alignas(16) f16 sB[128 * 64];
  const int tid = threadIdx.x;
  const int w = tid >> 6, l = tid & 63;
  const int lr = l & 15, lk = l >> 4;
  const int tm0 = blockIdx.y * 128, tn0 = blockIdx.x * 128;
  const int wm = (w >> 1) * 64, wn = (w & 1) * 64;

  f32x4 acc[4][4] = {};

  for (int k0 = 0; k0 < K; k0 += 64) {
#pragma unroll
    for (int i = 0; i < 4; ++i) {
      int slot = i * 256 + tid;
      int row = slot >> 3;
      int cg = (slot & 7) ^ (row & 7);
      load_lds16(A + (size_t)(tm0 + row) * K + k0 + cg * 8, &sA[(size_t)(i * 256 + (w << 6)) * 8]);
      load_lds16(B + (size_t)(tn0 + row) * K + k0 + cg * 8, &sB[(size_t)(i * 256 + (w << 6)) * 8]);
    }
    __syncthreads();
#pragma unroll
    for (int kk = 0; kk < 2; ++kk) {
      f16x8 af[4], bf[4];
#pragma unroll
      for (int t = 0; t < 4; ++t) {
        int rowA = wm + t * 16 + lr;
        af[t] = *(const f16x8*)&sA[rowA * 64 + ((kk * 4 + lk) ^ (rowA & 7)) * 8];
        int rowB = wn + t * 16 + lr;
        bf[t] = *(const f16x8*)&sB[rowB * 64 + ((kk * 4 + lk) ^ (rowB & 7)) * 8];
      }
#pragma unroll
      for (int mt = 0; mt < 4; ++mt)
#pragma unroll
        for (int nt = 0; nt < 4; ++nt) acc[mt][nt] = MFMA16(af[mt], bf[nt], acc[mt][nt]);
    }
    __syncthreads();
  }

#pragma unroll
  for (int mt = 0; mt < 4; ++mt)
#pragma unroll
    for (int nt = 0; nt < 4; ++nt)
#pragma unroll
      for (int r = 0; r < 4; ++r) {
        int m = tm0 + wm + mt * 16 + lk * 4 + r;
        int n = tn0 + wn + nt * 16 + lr;
        float val = acc[mt][nt][r];
        if constexpr (MODE == 0) {
          bool im = n >= 3072;
          int nn = im ? n - 3072 : n;
          float v2 = val + (im ? p.bpi[nn] : p.bpr[nn]);
          int part = nn >> 10;
          int e = nn & 1023, h = e >> 6, d = e & 63;
          int bb = m >> 10, s = m & 1023;
          size_t bh = (size_t)bb * 16 + h;
          if (part == 0) {
            p.QC[(bh * 1024 + s) * 128 + (im ? 64 : 0) + d] = (f16)(v2 * 0.125f);
          } else if (part == 1) {
            size_t o = (bh * 1024 + s) * 128;
            if (!im) { p.KCr[o + d] = (f16)v2; p.KCi[o + 64 + d] = (f16)v2; }
            else     { p.KCr[o + 64 + d] = (f16)(-v2); p.KCi[o + d] = (f16)v2; }
          } else {
            p.VCT[(bh * 128 + (im ? 64 : 0) + d) * 1024 + s] = (f16)v2;
          }
        } else {
          if (n < 1024) {
            float v2 = val + p.bor[n];
            if (p.out_complex) p.out[((size_t)m * 1024 + n) * 2] = v2;
            else p.out[(size_t)m * 1024 + n] = v2;
          } else {
            if (p.out_complex) p.out[((size_t)m * 1024 + n - 1024) * 2 + 1] = val + p.boi[n - 1024];
          }
        }
      }
}

// ---------------- flash-style complex attention -------------------------------
// grid = B*H*16 blocks; block = 4 waves; wave handles 16 q-rows; KBLK=32.
// K/V staged in LDS once per block (shared by 4 waves), XOR-chunk swizzled
// 128B rows; P tile swizzled; defer-max (THR=8) skips acc rescale.

__global__ __launch_bounds__(256, 4) void attn_kernel(const f16* __restrict__ QC,
                                                      const f16* __restrict__ KCr,
                                                      const f16* __restrict__ KCi,
                                                      const f16* __restrict__ VCT,
                                                      f16* __restrict__ OC) {
  __shared__ alignas(16) f16 sKr[32 * 128];   // logical [krow32][col128], phys 64 rows x 128B
  __shared__ alignas(16) f16 sKi[32 * 128];
  __shared__ alignas(16) f16 sV[128 * 32];    // logical [feat128][k32], phys 64 rows x 128B
  __shared__ alignas(16) f16 sP[4 * 2 * 16 * 32];  // per-wave 16x32, phys 8 rows x 128B
  const int tid = threadIdx.x;
  const int w = tid >> 6, l = tid & 63;
  const int lr = l & 15, lk = l >> 4;
  const int bid = blockIdx.x;
  const int qt = bid & 15;
  const int bh = bid >> 4;
  const int q0 = qt * 64 + w * 16;
  const f16* Qb = QC + (size_t)bh * 1024 * 128;
  const f16* Krb = KCr + (size_t)bh * 1024 * 128;
  const f16* Kib = KCi + (size_t)bh * 1024 * 128;
  const f16* Vb = VCT + (size_t)bh * 128 * 1024;

  f16x8 qf[4];
#pragma unroll
  for (int c = 0; c < 4; ++c)
    qf[c] = *(const f16x8*)&Qb[(size_t)(q0 + lr) * 128 + c * 32 + lk * 8];

  f32x4 accR[8] = {};
  f32x4 accI[8] = {};
  float m_r[4], l_r[4], m_i[4], l_i[4];
#pragma unroll
  for (int r = 0; r < 4; ++r) { m_r[r] = -1e30f; l_r[r] = 0.f; m_i[r] = -1e30f; l_i[r] = 0.f; }

  for (int k0 = 0; k0 < 1024; k0 += 32) {
    // ---- stage K/V tiles into LDS (linear dest, inverse-swizzled source) ----
#pragma unroll
    for (int i = 0; i < 2; ++i) {
      int slot = i * 256 + tid;
      int row = slot >> 3;                 // 128B phys row
      int chs = (slot & 7) ^ (row & 7);    // source logical chunk
      int ldsOff = (i * 256 + (w << 6)) * 8;  // f16 units, wave-uniform
      const f16* gkr = Krb + (size_t)(k0 + (row >> 1)) * 128 + (row & 1) * 64 + chs * 8;
      load_lds16(gkr, &sKr[ldsOff]);
      const f16* gki = Kib + (size_t)(k0 + (row >> 1)) * 128 + (row & 1) * 64 + chs * 8;
      load_lds16(gki, &sKi[ldsOff]);
      const f16* gv = Vb + (size_t)(row * 2 + (chs >> 2)) * 1024 + k0 + (chs & 3) * 8;
      load_lds16(gv, &sV[ldsOff]);
    }
    __syncthreads();

    // ---- QK^T from LDS (swizzled reads) ----
    f32x4 sr[2] = {}, si[2] = {};
#pragma unroll
    for (int c = 0; c < 4; ++c) {
#pragma unroll
      for (int nt = 0; nt < 2; ++nt) {
        int krow = nt * 16 + lr;
        int row128 = krow * 2 + (c >> 1);
        int chp = (((c & 1) * 4 + lk) ^ (row128 & 7)) * 8;
        f16x8 kr = *(const f16x8*)&sKr[row128 * 64 + chp];
        f16x8 ki = *(const f16x8*)&sKi[row128 * 64 + chp];
        sr[nt] = MFMA16(qf[c], kr, sr[nt]);
        si[nt] = MFMA16(qf[c], ki, si[nt]);
      }
    }

    // ---- online softmax (defer-max THR=8), P -> swizzled LDS ----
    f16* sPw0 = &sP[(w * 2 + 0) * 512];
    f16* sPw1 = &sP[(w * 2 + 1) * 512];
#pragma unroll
    for (int r = 0; r < 4; ++r) {
      int q = lk * 4 + r;
      int prow = q >> 1;
      int cb = (q & 1) * 4;
      {
        float vm = rmax16(fmaxf(sr[0][r], sr[1][r]));
        if (vm > m_r[r] + 8.f) {
          float sc = __expf(m_r[r] - vm);
          l_r[r] *= sc;
#pragma unroll
          for (int t = 0; t < 8; ++t) accR[t][r] *= sc;
          m_r[r] = vm;
        }
        float p0 = __expf(sr[0][r] - m_r[r]);
        float p1 = __expf(sr[1][r] - m_r[r]);
        l_r[r] += rsum16(p0 + p1);
        sPw0[prow * 64 + ((cb + (lr >> 3)) ^ (prow & 7)) * 8 + (lr & 7)] = (f16)p0;
        sPw0[prow * 64 + ((cb + 2 + (lr >> 3)) ^ (prow & 7)) * 8 + (lr & 7)] = (f16)p1;
      }
      {
        float vm = rmax16(fmaxf(si[0][r], si[1][r]));
        if (vm > m_i[r] + 8.f) {
          float sc = __expf(m_i[r] - vm);
          l_i[r] *= sc;
#pragma unroll
          for (int t = 0; t < 8; ++t) accI[t][r] *= sc;
          m_i[r] = vm;
        }
        float p0 = __expf(si[0][r] - m_i[r]);
        float p1 = __expf(si[1][r] - m_i[r]);
        l_i[r] += rsum16(p0 + p1);
        sPw1[prow * 64 + ((cb + (lr >> 3)) ^ (prow & 7)) * 8 + (lr & 7)] = (f16)p0;
        sPw1[prow * 64 + ((cb + 2 + (lr >> 3)) ^ (prow & 7)) * 8 + (lr & 7)] = (f16)p1;
      }
    }

    // ---- P fragments (swizzled read) ----
    int prow = lr >> 1;
    int pch = (((lr & 1) * 4 + lk) ^ (prow & 7)) * 8;
    f16x8 pr = *(const f16x8*)&sPw0[prow * 64 + pch];
    f16x8 pi = *(const f16x8*)&sPw1[prow * 64 + pch];

    // ---- PV from LDS V (swizzled read) ----
#pragma unroll
    for (int f = 0; f < 8; ++f) {
      int feat = f * 16 + lr;
      int vrow = feat >> 1;
      int vch = (((feat & 1) * 4 + lk) ^ (vrow & 7)) * 8;
      f16x8 vf = *(const f16x8*)&sV[vrow * 64 + vch];
      accR[f] = MFMA16(pr, vf, accR[f]);
      accI[f] = MFMA16(pi, vf, accI[f]);
    }
    __syncthreads();
  }

  const int bb = bh >> 4, h = bh & 15;
#pragma unroll
  for (int t = 0; t < 4; ++t)
#pragma unroll
    for (int r = 0; r < 4; ++r) {
      int qrow = q0 + lk * 4 + r;
      size_t m = (size_t)bb * 1024 + qrow;
      int d = t * 16 + lr;
      float ilr = 1.f / l_r[r], ili = 1.f / l_i[r];
      float orv = accR[t][r] * ilr - accI[t + 4][r] * ili;
      float oiv = accR[t + 4][r] * ilr + accI[t][r] * ili;
      OC[m * 2048 + h * 64 + d] = (f16)orv;
      OC[m * 2048 + 1024 + h * 64 + d] = (f16)oiv;
    }
}

// ---------------- launcher ----------------------------------------------------

extern "C" void kernel_launch(void* const* d_in, const int* in_sizes, int n_in,
                              void* d_out, int out_size, void* d_ws, size_t ws_size,
                              hipStream_t stream) {
  const float* xr = (const float*)d_in[0];
  const float* xi = (const float*)d_in[1];
  const float* wpr = (const float*)d_in[2];
  const float* wpi = (const float*)d_in[3];
  const float* bpr = (const float*)d_in[4];
  const float* bpi = (const float*)d_in[5];
  const float* wor = (const float*)d_in[6];
  const float* woi = (const float*)d_in[7];
  const float* bor = (const float*)d_in[8];
  const float* boi = (const float*)d_in[9];

  f16* ws = (f16*)d_ws;
  f16* XC = ws;                       // 4096*2048
  f16* WQKV = XC + 8388608;           // 6144*2048
  f16* QC = WQKV + 12582912;          // 64*1024*128
  f16* KCr = QC + 8388608;
  f16* KCi = KCr + 8388608;
  f16* VCT = KCi + 8388608;           // 64*128*1024
  f16* OC = VCT + 8388608;            // 4096*2048
  f16* WOUT = OC + 8388608;           // 2048*2048

  pack_x_kernel<<<8192, 256, 0, stream>>>(xr, xi, XC);
  pack_wqkv_kernel<<<12288, 256, 0, stream>>>(wpr, wpi, WQKV);
  pack_wout_kernel<<<4096, 256, 0, stream>>>(wor, woi, WOUT);

  GemmParams p1 = {};
  p1.QC = QC; p1.KCr = KCr; p1.KCi = KCi; p1.VCT = VCT;
  p1.bpr = bpr; p1.bpi = bpi;
  gemm_kernel<0><<<dim3(48, 32), 256, 0, stream>>>(XC, WQKV, p1);

  attn_kernel<<<1024, 256, 0, stream>>>(QC, KCr, KCi, VCT, OC);

  GemmParams p2 = {};
  p2.out = (float*)d_out; p2.bor = bor; p2.boi = boi;
  p2.out_complex = (out_size == 8388608) ? 1 : 0;
  int ntilesN = p2.out_complex ? 16 : 8;
  gemm_kernel<1><<<dim3(ntilesN, 32), 256, 0, stream>>>(OC, WOUT, p2);
}

// Round 3
// 501.667 us; speedup vs baseline: 1.3256x; 1.0471x over previous
//
#include <hip/hip_runtime.h>

// Complex MHA, B=4 S=1024 E=1024 H=16 DH=64.
// pack(fp32->fp16, K-concat complex trick) -> GEMM1 (QKV proj, scatter epilogue)
// -> flash complex attention (8-wave QBLK=128, XCD-local, double-buffered LDS K/V)
// -> GEMM2 (out proj).

typedef _Float16 f16;
typedef _Float16 f16x8 __attribute__((ext_vector_type(8)));
typedef _Float16 f16x4 __attribute__((ext_vector_type(4)));
typedef float f32x4 __attribute__((ext_vector_type(4)));

#define MFMA16(a, b, c) __builtin_amdgcn_mfma_f32_16x16x32_f16(a, b, c, 0, 0, 0)

__device__ inline void load_lds16(const void* g, void* l) {
  __builtin_amdgcn_global_load_lds(
      (const __attribute__((address_space(1))) unsigned int*)g,
      (__attribute__((address_space(3))) unsigned int*)l, 16, 0, 0);
}

__device__ inline float rmax16(float v) {
#pragma unroll
  for (int m = 1; m < 16; m <<= 1) v = fmaxf(v, __shfl_xor(v, m));
  return v;
}
__device__ inline float rsum16(float v) {
#pragma unroll
  for (int m = 1; m < 16; m <<= 1) v += __shfl_xor(v, m);
  return v;
}

// ---------------- pack kernels (fp32 -> fp16, concat layouts) ----------------

__global__ void pack_x_kernel(const float* __restrict__ xr, const float* __restrict__ xi,
                              f16* __restrict__ XC) {
  int i = blockIdx.x * 256 + threadIdx.x;
  if (i >= (4096 * 2048 / 4)) return;
  int idx = i * 4;
  int m = idx >> 11, k = idx & 2047;
  const float* src = (k < 1024) ? (xr + (size_t)m * 1024 + k) : (xi + (size_t)m * 1024 + k - 1024);
  float4 v = *(const float4*)src;
  f16x4 o = {(f16)v.x, (f16)v.y, (f16)v.z, (f16)v.w};
  *(f16x4*)(XC + idx) = o;
}

__global__ void pack_wqkv_kernel(const float* __restrict__ wr, const float* __restrict__ wi,
                                 f16* __restrict__ W) {
  int i = blockIdx.x * 256 + threadIdx.x;
  if (i >= (6144 * 2048 / 4)) return;
  int idx = i * 4;
  int n = idx >> 11, k = idx & 2047;
  const float* base;
  float sgn = 1.f;
  if (n < 3072) {
    if (k < 1024) base = wr + (size_t)n * 1024 + k;
    else { base = wi + (size_t)n * 1024 + k - 1024; sgn = -1.f; }
  } else {
    int n2 = n - 3072;
    if (k < 1024) base = wi + (size_t)n2 * 1024 + k;
    else base = wr + (size_t)n2 * 1024 + k - 1024;
  }
  float4 v = *(const float4*)base;
  f16x4 o = {(f16)(sgn * v.x), (f16)(sgn * v.y), (f16)(sgn * v.z), (f16)(sgn * v.w)};
  *(f16x4*)(W + idx) = o;
}

__global__ void pack_wout_kernel(const float* __restrict__ wor, const float* __restrict__ woi,
                                 f16* __restrict__ W) {
  int i = blockIdx.x * 256 + threadIdx.x;
  if (i >= (2048 * 2048 / 4)) return;
  int idx = i * 4;
  int n = idx >> 11, k = idx & 2047;
  const float* base;
  float sgn = 1.f;
  if (n < 1024) {
    if (k < 1024) base = wor + (size_t)n * 1024 + k;
    else { base = woi + (size_t)n * 1024 + k - 1024; sgn = -1.f; }
  } else {
    int n2 = n - 1024;
    if (k < 1024) base = woi + (size_t)n2 * 1024 + k;
    else base = wor + (size_t)n2 * 1024 + k - 1024;
  }
  float4 v = *(const float4*)base;
  f16x4 o = {(f16)(sgn * v.x), (f16)(sgn * v.y), (f16)(sgn * v.z), (f16)(sgn * v.w)};
  *(f16x4*)(W + idx) = o;
}

// ---------------- GEMM: C[M,N] = A[M,K=2048] * B[N,K=2048]^T -------------------

struct GemmParams {
  f16 *QC, *KCr, *KCi, *VCT;
  const float *bpr, *bpi;
  float* out;
  const float *bor, *boi;
  int out_complex;
};

template <int MODE>
__global__ __launch_bounds__(256) void gemm_kernel(const f16* __restrict__ A,
                                                   const f16* __restrict__ B,
                                                   GemmParams p) {
  const int K = 2048;
  __shared__ alignas(16) f16 sA[128 * 64];
  __shared__ alignas(16) f16 sB[128 * 64];
  const int tid = threadIdx.x;
  const int w = tid >> 6, l = tid & 63;
  const int lr = l & 15, lk = l >> 4;
  // bijective XCD-aware swizzle (T1/m204)
  const int nwg = gridDim.x * gridDim.y;
  const int lin = blockIdx.y * gridDim.x + blockIdx.x;
  const int qq = nwg >> 3, rr = nwg & 7;
  const int xcd = lin & 7, off = lin >> 3;
  const int swz = (xcd < rr ? xcd * (qq + 1) : rr * (qq + 1) + (xcd - rr) * qq) + off;
  const int tm0 = (swz / gridDim.x) * 128;
  const int tn0 = (swz % gridDim.x) * 128;
  const int wm = (w >> 1) * 64, wn = (w & 1) * 64;

  f32x4 acc[4][4] = {};

  for (int k0 = 0; k0 < K; k0 += 64) {
#pragma unroll
    for (int i = 0; i < 4; ++i) {
      int slot = i * 256 + tid;
      int row = slot >> 3;
      int cg = (slot & 7) ^ (row & 7);
      load_lds16(A + (size_t)(tm0 + row) * K + k0 + cg * 8, &sA[(size_t)(i * 256 + (w << 6)) * 8]);
      load_lds16(B + (size_t)(tn0 + row) * K + k0 + cg * 8, &sB[(size_t)(i * 256 + (w << 6)) * 8]);
    }
    __syncthreads();
#pragma unroll
    for (int kk = 0; kk < 2; ++kk) {
      f16x8 af[4], bf[4];
#pragma unroll
      for (int t = 0; t < 4; ++t) {
        int rowA = wm + t * 16 + lr;
        af[t] = *(const f16x8*)&sA[rowA * 64 + ((kk * 4 + lk) ^ (rowA & 7)) * 8];
        int rowB = wn + t * 16 + lr;
        bf[t] = *(const f16x8*)&sB[rowB * 64 + ((kk * 4 + lk) ^ (rowB & 7)) * 8];
      }
#pragma unroll
      for (int mt = 0; mt < 4; ++mt)
#pragma unroll
        for (int nt = 0; nt < 4; ++nt) acc[mt][nt] = MFMA16(af[mt], bf[nt], acc[mt][nt]);
    }
    __syncthreads();
  }

#pragma unroll
  for (int mt = 0; mt < 4; ++mt)
#pragma unroll
    for (int nt = 0; nt < 4; ++nt)
#pragma unroll
      for (int r = 0; r < 4; ++r) {
        int m = tm0 + wm + mt * 16 + lk * 4 + r;
        int n = tn0 + wn + nt * 16 + lr;
        float val = acc[mt][nt][r];
        if constexpr (MODE == 0) {
          bool im = n >= 3072;
          int nn = im ? n - 3072 : n;
          float v2 = val + (im ? p.bpi[nn] : p.bpr[nn]);
          int part = nn >> 10;
          int e = nn & 1023, h = e >> 6, d = e & 63;
          int bb = m >> 10, s = m & 1023;
          size_t bh = (size_t)bb * 16 + h;
          if (part == 0) {
            p.QC[(bh * 1024 + s) * 128 + (im ? 64 : 0) + d] = (f16)(v2 * 0.125f);
          } else if (part == 1) {
            size_t o = (bh * 1024 + s) * 128;
            if (!im) { p.KCr[o + d] = (f16)v2; p.KCi[o + 64 + d] = (f16)v2; }
            else     { p.KCr[o + 64 + d] = (f16)(-v2); p.KCi[o + d] = (f16)v2; }
          } else {
            p.VCT[(bh * 128 + (im ? 64 : 0) + d) * 1024 + s] = (f16)v2;
          }
        } else {
          if (n < 1024) {
            float v2 = val + p.bor[n];
            if (p.out_complex) p.out[((size_t)m * 1024 + n) * 2] = v2;
            else p.out[(size_t)m * 1024 + n] = v2;
          } else {
            if (p.out_complex) p.out[((size_t)m * 1024 + n - 1024) * 2 + 1] = val + p.boi[n - 1024];
          }
        }
      }
}

// ---------------- flash-style complex attention -------------------------------
// grid = 512 blocks (8 per head, XCD-local), block = 8 waves, QBLK=128, KBLK=32.
// K/V double-buffered in LDS via global_load_lds (XOR-chunk swizzled 128B rows);
// P tile swizzled; defer-max (THR=8).

__global__ __launch_bounds__(512, 4) void attn_kernel(const f16* __restrict__ QC,
                                                      const f16* __restrict__ KCr,
                                                      const f16* __restrict__ KCi,
                                                      const f16* __restrict__ VCT,
                                                      f16* __restrict__ OC) {
  __shared__ alignas(16) f16 sKr[2][32 * 128];
  __shared__ alignas(16) f16 sKi[2][32 * 128];
  __shared__ alignas(16) f16 sV[2][128 * 32];
  __shared__ alignas(16) f16 sP[8][2][16 * 32];
  const int tid = threadIdx.x;
  const int w = tid >> 6, l = tid & 63;
  const int lr = l & 15, lk = l >> 4;
  // XCD-locality decode: all 8 q-tile blocks of a head share bid%8 (= bh%8)
  const int bid = blockIdx.x;
  const int xx = bid & 7, yy = bid >> 3;
  const int bh = xx + ((yy >> 3) << 3);
  const int qt = yy & 7;
  const int q0 = qt * 128 + w * 16;
  const f16* Qb = QC + (size_t)bh * 1024 * 128;
  const f16* Krb = KCr + (size_t)bh * 1024 * 128;
  const f16* Kib = KCi + (size_t)bh * 1024 * 128;
  const f16* Vb = VCT + (size_t)bh * 128 * 1024;

  f16x8 qf[4];
#pragma unroll
  for (int c = 0; c < 4; ++c)
    qf[c] = *(const f16x8*)&Qb[(size_t)(q0 + lr) * 128 + c * 32 + lk * 8];

  f32x4 accR[8] = {};
  f32x4 accI[8] = {};
  float m_r[4], l_r[4], m_i[4], l_i[4];
#pragma unroll
  for (int r = 0; r < 4; ++r) { m_r[r] = -1e30f; l_r[r] = 0.f; m_i[r] = -1e30f; l_i[r] = 0.f; }

  // staging addresses (per-lane global source, wave-uniform LDS dest)
  const int srow = tid >> 3;                 // 128B phys row (0..63)
  const int schs = (tid & 7) ^ (srow & 7);   // inverse-swizzled source chunk
  const f16* gKr = Krb + (size_t)(srow >> 1) * 128 + (srow & 1) * 64 + schs * 8;
  const f16* gKi = Kib + (size_t)(srow >> 1) * 128 + (srow & 1) * 64 + schs * 8;
  const f16* gV = Vb + (size_t)(srow * 2 + (schs >> 2)) * 1024 + (schs & 3) * 8;
  const int ldsW = w * 512;                  // wave-uniform f16 offset

#define STAGE(s, k0)                                   \
  do {                                                 \
    load_lds16(gKr + (size_t)(k0) * 128, &sKr[s][ldsW]); \
    load_lds16(gKi + (size_t)(k0) * 128, &sKi[s][ldsW]); \
    load_lds16(gV + (k0), &sV[s][ldsW]);               \
  } while (0)

  STAGE(0, 0);
  asm volatile("s_waitcnt vmcnt(0)" ::: "memory");
  __syncthreads();
  int cur = 0;

  for (int t = 0; t < 32; ++t) {
    if (t < 31) STAGE(cur ^ 1, (t + 1) * 32);

    // ---- QK^T from LDS (swizzled reads) ----
    f32x4 sr[2] = {}, si[2] = {};
#pragma unroll
    for (int c = 0; c < 4; ++c) {
#pragma unroll
      for (int nt = 0; nt < 2; ++nt) {
        int krow = nt * 16 + lr;
        int row128 = krow * 2 + (c >> 1);
        int chp = (((c & 1) * 4 + lk) ^ (row128 & 7)) * 8;
        f16x8 kr = *(const f16x8*)&sKr[cur][row128 * 64 + chp];
        f16x8 ki = *(const f16x8*)&sKi[cur][row128 * 64 + chp];
        sr[nt] = MFMA16(qf[c], kr, sr[nt]);
        si[nt] = MFMA16(qf[c], ki, si[nt]);
      }
    }

    // ---- online softmax (defer-max THR=8), P -> swizzled LDS ----
    f16* sPw0 = &sP[w][0][0];
    f16* sPw1 = &sP[w][1][0];
#pragma unroll
    for (int r = 0; r < 4; ++r) {
      int q = lk * 4 + r;
      int prow = q >> 1;
      int cb = (q & 1) * 4;
      {
        float vm = rmax16(fmaxf(sr[0][r], sr[1][r]));
        if (vm > m_r[r] + 8.f) {
          float sc = __expf(m_r[r] - vm);
          l_r[r] *= sc;
#pragma unroll
          for (int t2 = 0; t2 < 8; ++t2) accR[t2][r] *= sc;
          m_r[r] = vm;
        }
        float p0 = __expf(sr[0][r] - m_r[r]);
        float p1 = __expf(sr[1][r] - m_r[r]);
        l_r[r] += rsum16(p0 + p1);
        sPw0[prow * 64 + ((cb + (lr >> 3)) ^ (prow & 7)) * 8 + (lr & 7)] = (f16)p0;
        sPw0[prow * 64 + ((cb + 2 + (lr >> 3)) ^ (prow & 7)) * 8 + (lr & 7)] = (f16)p1;
      }
      {
        float vm = rmax16(fmaxf(si[0][r], si[1][r]));
        if (vm > m_i[r] + 8.f) {
          float sc = __expf(m_i[r] - vm);
          l_i[r] *= sc;
#pragma unroll
          for (int t2 = 0; t2 < 8; ++t2) accI[t2][r] *= sc;
          m_i[r] = vm;
        }
        float p0 = __expf(si[0][r] - m_i[r]);
        float p1 = __expf(si[1][r] - m_i[r]);
        l_i[r] += rsum16(p0 + p1);
        sPw1[prow * 64 + ((cb + (lr >> 3)) ^ (prow & 7)) * 8 + (lr & 7)] = (f16)p0;
        sPw1[prow * 64 + ((cb + 2 + (lr >> 3)) ^ (prow & 7)) * 8 + (lr & 7)] = (f16)p1;
      }
    }

    // ---- P fragments (swizzled read) ----
    int prow = lr >> 1;
    int pch = (((lr & 1) * 4 + lk) ^ (prow & 7)) * 8;
    f16x8 pr = *(const f16x8*)&sPw0[prow * 64 + pch];
    f16x8 pi = *(const f16x8*)&sPw1[prow * 64 + pch];

    // ---- PV from LDS V (swizzled read) ----
#pragma unroll
    for (int f = 0; f < 8; ++f) {
      int feat = f * 16 + lr;
      int vrow = feat >> 1;
      int vch = (((feat & 1) * 4 + lk) ^ (vrow & 7)) * 8;
      f16x8 vf = *(const f16x8*)&sV[cur][vrow * 64 + vch];
      accR[f] = MFMA16(pr, vf, accR[f]);
      accI[f] = MFMA16(pi, vf, accI[f]);
    }

    asm volatile("s_waitcnt vmcnt(0)" ::: "memory");
    __syncthreads();
    cur ^= 1;
  }
#undef STAGE

  const int bb = bh >> 4, h = bh & 15;
#pragma unroll
  for (int t = 0; t < 4; ++t)
#pragma unroll
    for (int r = 0; r < 4; ++r) {
      int qrow = q0 + lk * 4 + r;
      size_t m = (size_t)bb * 1024 + qrow;
      int d = t * 16 + lr;
      float ilr = 1.f / l_r[r], ili = 1.f / l_i[r];
      float orv = accR[t][r] * ilr - accI[t + 4][r] * ili;
      float oiv = accR[t + 4][r] * ilr + accI[t][r] * ili;
      OC[m * 2048 + h * 64 + d] = (f16)orv;
      OC[m * 2048 + 1024 + h * 64 + d] = (f16)oiv;
    }
}

// ---------------- launcher ----------------------------------------------------

extern "C" void kernel_launch(void* const* d_in, const int* in_sizes, int n_in,
                              void* d_out, int out_size, void* d_ws, size_t ws_size,
                              hipStream_t stream) {
  const float* xr = (const float*)d_in[0];
  const float* xi = (const float*)d_in[1];
  const float* wpr = (const float*)d_in[2];
  const float* wpi = (const float*)d_in[3];
  const float* bpr = (const float*)d_in[4];
  const float* bpi = (const float*)d_in[5];
  const float* wor = (const float*)d_in[6];
  const float* woi = (const float*)d_in[7];
  const float* bor = (const float*)d_in[8];
  const float* boi = (const float*)d_in[9];

  f16* ws = (f16*)d_ws;
  f16* XC = ws;                       // 4096*2048
  f16* WQKV = XC + 8388608;           // 6144*2048
  f16* QC = WQKV + 12582912;          // 64*1024*128
  f16* KCr = QC + 8388608;
  f16* KCi = KCr + 8388608;
  f16* VCT = KCi + 8388608;           // 64*128*1024
  f16* OC = VCT + 8388608;            // 4096*2048
  f16* WOUT = OC + 8388608;           // 2048*2048

  pack_x_kernel<<<8192, 256, 0, stream>>>(xr, xi, XC);
  pack_wqkv_kernel<<<12288, 256, 0, stream>>>(wpr, wpi, WQKV);
  pack_wout_kernel<<<4096, 256, 0, stream>>>(wor, woi, WOUT);

  GemmParams p1 = {};
  p1.QC = QC; p1.KCr = KCr; p1.KCi = KCi; p1.VCT = VCT;
  p1.bpr = bpr; p1.bpi = bpi;
  gemm_kernel<0><<<dim3(48, 32), 256, 0, stream>>>(XC, WQKV, p1);

  attn_kernel<<<512, 512, 0, stream>>>(QC, KCr, KCi, VCT, OC);

  GemmParams p2 = {};
  p2.out = (float*)d_out; p2.bor = bor; p2.boi = boi;
  p2.out_complex = (out_size == 8388608) ? 1 : 0;
  int ntilesN = p2.out_complex ? 16 : 8;
  gemm_kernel<1><<<dim3(ntilesN, 32), 256, 0, stream>>>(OC, WOUT, p2);
}

// Round 5
// 319.220 us; speedup vs baseline: 2.0832x; 1.5715x over previous
//
#include <hip/hip_runtime.h>

// Complex MHA, B=4 S=1024 E=1024 H=16 DH=64.
// pack(fp32->fp16, K-concat complex trick) -> GEMM1 (QKV proj, scatter epilogue)
// -> flash complex attention (m214-style: 8 waves x 32 q-rows, 32x32 MFMA,
//    swapped QK^T and PV so softmax is lane-local; cvt_pkrtz+permlane32_swap;
//    defer-max; LDS-dbuf K/V) -> GEMM2 (out proj).

typedef _Float16 f16;
typedef _Float16 f16x8 __attribute__((ext_vector_type(8)));
typedef _Float16 f16x4 __attribute__((ext_vector_type(4)));
typedef float f32x4 __attribute__((ext_vector_type(4)));
typedef float f32x16 __attribute__((ext_vector_type(16)));

#define MFMA16(a, b, c) __builtin_amdgcn_mfma_f32_16x16x32_f16(a, b, c, 0, 0, 0)
#define MFMA32(a, b, c) __builtin_amdgcn_mfma_f32_32x32x16_f16(a, b, c, 0, 0, 0)

__device__ inline void load_lds16(const void* g, void* l) {
  __builtin_amdgcn_global_load_lds(
      (const __attribute__((address_space(1))) unsigned int*)g,
      (__attribute__((address_space(3))) unsigned int*)l, 16, 0, 0);
}

__device__ inline unsigned pkrtz(float a, float b) {
  auto t = __builtin_amdgcn_cvt_pkrtz(a, b);  // __fp16 ext_vector(2)
  return __builtin_bit_cast(unsigned, t);
}

// ---------------- pack kernels (fp32 -> fp16, concat layouts) ----------------

__global__ void pack_x_kernel(const float* __restrict__ xr, const float* __restrict__ xi,
                              f16* __restrict__ XC) {
  int i = blockIdx.x * 256 + threadIdx.x;
  if (i >= (4096 * 2048 / 4)) return;
  int idx = i * 4;
  int m = idx >> 11, k = idx & 2047;
  const float* src = (k < 1024) ? (xr + (size_t)m * 1024 + k) : (xi + (size_t)m * 1024 + k - 1024);
  float4 v = *(const float4*)src;
  f16x4 o = {(f16)v.x, (f16)v.y, (f16)v.z, (f16)v.w};
  *(f16x4*)(XC + idx) = o;
}

__global__ void pack_wqkv_kernel(const float* __restrict__ wr, const float* __restrict__ wi,
                                 f16* __restrict__ W) {
  int i = blockIdx.x * 256 + threadIdx.x;
  if (i >= (6144 * 2048 / 4)) return;
  int idx = i * 4;
  int n = idx >> 11, k = idx & 2047;
  const float* base;
  float sgn = 1.f;
  if (n < 3072) {
    if (k < 1024) base = wr + (size_t)n * 1024 + k;
    else { base = wi + (size_t)n * 1024 + k - 1024; sgn = -1.f; }
  } else {
    int n2 = n - 3072;
    if (k < 1024) base = wi + (size_t)n2 * 1024 + k;
    else base = wr + (size_t)n2 * 1024 + k - 1024;
  }
  float4 v = *(const float4*)base;
  f16x4 o = {(f16)(sgn * v.x), (f16)(sgn * v.y), (f16)(sgn * v.z), (f16)(sgn * v.w)};
  *(f16x4*)(W + idx) = o;
}

__global__ void pack_wout_kernel(const float* __restrict__ wor, const float* __restrict__ woi,
                                 f16* __restrict__ W) {
  int i = blockIdx.x * 256 + threadIdx.x;
  if (i >= (2048 * 2048 / 4)) return;
  int idx = i * 4;
  int n = idx >> 11, k = idx & 2047;
  const float* base;
  float sgn = 1.f;
  if (n < 1024) {
    if (k < 1024) base = wor + (size_t)n * 1024 + k;
    else { base = woi + (size_t)n * 1024 + k - 1024; sgn = -1.f; }
  } else {
    int n2 = n - 1024;
    if (k < 1024) base = woi + (size_t)n2 * 1024 + k;
    else base = wor + (size_t)n2 * 1024 + k - 1024;
  }
  float4 v = *(const float4*)base;
  f16x4 o = {(f16)(sgn * v.x), (f16)(sgn * v.y), (f16)(sgn * v.z), (f16)(sgn * v.w)};
  *(f16x4*)(W + idx) = o;
}

// ---------------- GEMM: C[M,N] = A[M,K=2048] * B[N,K=2048]^T -------------------

struct GemmParams {
  f16 *QC, *KCr, *KCi, *VCT;
  const float *bpr, *bpi;
  float* out;
  const float *bor, *boi;
  int out_complex;
};

template <int MODE>
__global__ __launch_bounds__(256) void gemm_kernel(const f16* __restrict__ A,
                                                   const f16* __restrict__ B,
                                                   GemmParams p) {
  const int K = 2048;
  __shared__ alignas(16) f16 sA[128 * 64];
  __shared__ alignas(16) f16 sB[128 * 64];
  const int tid = threadIdx.x;
  const int w = tid >> 6, l = tid & 63;
  const int lr = l & 15, lk = l >> 4;
  const int nwg = gridDim.x * gridDim.y;
  const int lin = blockIdx.y * gridDim.x + blockIdx.x;
  const int qq = nwg >> 3, rr = nwg & 7;
  const int xcd = lin & 7, off = lin >> 3;
  const int swz = (xcd < rr ? xcd * (qq + 1) : rr * (qq + 1) + (xcd - rr) * qq) + off;
  const int tm0 = (swz / gridDim.x) * 128;
  const int tn0 = (swz % gridDim.x) * 128;
  const int wm = (w >> 1) * 64, wn = (w & 1) * 64;

  f32x4 acc[4][4] = {};

  for (int k0 = 0; k0 < K; k0 += 64) {
#pragma unroll
    for (int i = 0; i < 4; ++i) {
      int slot = i * 256 + tid;
      int row = slot >> 3;
      int cg = (slot & 7) ^ (row & 7);
      load_lds16(A + (size_t)(tm0 + row) * K + k0 + cg * 8, &sA[(size_t)(i * 256 + (w << 6)) * 8]);
      load_lds16(B + (size_t)(tn0 + row) * K + k0 + cg * 8, &sB[(size_t)(i * 256 + (w << 6)) * 8]);
    }
    __syncthreads();
#pragma unroll
    for (int kk = 0; kk < 2; ++kk) {
      f16x8 af[4], bf[4];
#pragma unroll
      for (int t = 0; t < 4; ++t) {
        int rowA = wm + t * 16 + lr;
        af[t] = *(const f16x8*)&sA[rowA * 64 + ((kk * 4 + lk) ^ (rowA & 7)) * 8];
        int rowB = wn + t * 16 + lr;
        bf[t] = *(const f16x8*)&sB[rowB * 64 + ((kk * 4 + lk) ^ (rowB & 7)) * 8];
      }
#pragma unroll
      for (int mt = 0; mt < 4; ++mt)
#pragma unroll
        for (int nt = 0; nt < 4; ++nt) acc[mt][nt] = MFMA16(af[mt], bf[nt], acc[mt][nt]);
    }
    __syncthreads();
  }

#pragma unroll
  for (int mt = 0; mt < 4; ++mt)
#pragma unroll
    for (int nt = 0; nt < 4; ++nt)
#pragma unroll
      for (int r = 0; r < 4; ++r) {
        int m = tm0 + wm + mt * 16 + lk * 4 + r;
        int n = tn0 + wn + nt * 16 + lr;
        float val = acc[mt][nt][r];
        if constexpr (MODE == 0) {
          bool im = n >= 3072;
          int nn = im ? n - 3072 : n;
          float v2 = val + (im ? p.bpi[nn] : p.bpr[nn]);
          int part = nn >> 10;
          int e = nn & 1023, h = e >> 6, d = e & 63;
          int bb = m >> 10, s = m & 1023;
          size_t bh = (size_t)bb * 16 + h;
          if (part == 0) {
            p.QC[(bh * 1024 + s) * 128 + (im ? 64 : 0) + d] = (f16)(v2 * 0.125f);
          } else if (part == 1) {
            size_t o = (bh * 1024 + s) * 128;
            if (!im) { p.KCr[o + d] = (f16)v2; p.KCi[o + 64 + d] = (f16)v2; }
            else     { p.KCr[o + 64 + d] = (f16)(-v2); p.KCi[o + d] = (f16)v2; }
          } else {
            p.VCT[(bh * 128 + (im ? 64 : 0) + d) * 1024 + s] = (f16)v2;
          }
        } else {
          if (n < 1024) {
            float v2 = val + p.bor[n];
            if (p.out_complex) p.out[((size_t)m * 1024 + n) * 2] = v2;
            else p.out[(size_t)m * 1024 + n] = v2;
          } else {
            if (p.out_complex) p.out[((size_t)m * 1024 + n - 1024) * 2 + 1] = val + p.boi[n - 1024];
          }
        }
      }
}

// ---------------- flash complex attention (swapped-operand 32x32) -------------
// grid = 256 blocks (4 per head, XCD-local), block = 8 waves, QBLK=256, KBLK=32.
// S' = mfma(K,Q): lane-local q column -> in-register softmax.
// O^T = mfma(V,P): lane-local q column -> per-lane rescale/normalize.

__global__ __launch_bounds__(512, 2) void attn_kernel(const f16* __restrict__ QC,
                                                      const f16* __restrict__ KCr,
                                                      const f16* __restrict__ KCi,
                                                      const f16* __restrict__ VCT,
                                                      f16* __restrict__ OC) {
  __shared__ alignas(16) f16 sKr[2][32 * 128];
  __shared__ alignas(16) f16 sKi[2][32 * 128];
  __shared__ alignas(16) f16 sV[2][128 * 32];
  const int tid = threadIdx.x;
  const int w = tid >> 6, l = tid & 63;
  const int lq = l & 31, hi = l >> 5;
  // XCD locality: 4 q-tile blocks of a head share bid%8 (== bh%8)
  const int bid = blockIdx.x;
  const int xx = bid & 7, yy = bid >> 3;
  const int bh = xx + ((yy >> 2) << 3);
  const int qt = yy & 3;
  const int q0 = qt * 256 + w * 32;
  const f16* Qb = QC + (size_t)bh * 1024 * 128;
  const f16* Krb = KCr + (size_t)bh * 1024 * 128;
  const f16* Kib = KCi + (size_t)bh * 1024 * 128;
  const f16* Vb = VCT + (size_t)bh * 128 * 1024;

  // Q fragments (B-operand): lane holds Q[q0+lq][c*16 + hi*8 .. +8]
  f16x8 qf[8];
#pragma unroll
  for (int c = 0; c < 8; ++c)
    qf[c] = *(const f16x8*)&Qb[(size_t)(q0 + lq) * 128 + c * 16 + hi * 8];

  f32x16 accR[4] = {};  // O^T tiles: Pr·[Vr|Vi], feat = t*32 + fr, col q = lq
  f32x16 accI[4] = {};  // Pi·[Vr|Vi]
  float m_r = -1e30f, l_r = 0.f, m_i = -1e30f, l_i = 0.f;

  // staging: linear LDS dest (tid*16B), inverse-swizzled global source
  // K tile [32 krow][128 feat] -> phys [64 rows][64 f16], chunk ^= (krow&7)
  const int sprow = tid >> 3;
  const int cK = (tid & 7) ^ ((tid >> 4) & 7);
  const f16* gKr = Krb + (size_t)(tid >> 4) * 128 + ((tid >> 3) & 1) * 64 + cK * 8;
  const f16* gKi = Kib + (size_t)(tid >> 4) * 128 + ((tid >> 3) & 1) * 64 + cK * 8;
  // V tile [128 feat][32 k] -> phys [64 rows][64 f16], chunk ^= (prow&7)
  const int cV = (tid & 7) ^ (sprow & 7);
  const f16* gV = Vb + (size_t)(sprow * 2 + (cV >> 2)) * 1024 + (cV & 3) * 8;
  const int ldsW = w * 512;

#define STAGE(s, k0)                                                 \
  do {                                                               \
    load_lds16(gKr + (size_t)(k0) * 128, &sKr[s][ldsW]);             \
    load_lds16(gKi + (size_t)(k0) * 128, &sKi[s][ldsW]);             \
    load_lds16(gV + (k0), &sV[s][ldsW]);                             \
  } while (0)

  STAGE(0, 0);
  asm volatile("s_waitcnt vmcnt(0)" ::: "memory");
  __syncthreads();
  int cur = 0;

  for (int t = 0; t < 32; ++t) {
    if (t < 31) STAGE(cur ^ 1, (t + 1) * 32);

    // ---- QK^T swapped: S'[k][q] = mfma(K_frag, Q_frag) ----
    f32x16 sr = {}, si = {};
    __builtin_amdgcn_s_setprio(1);
#pragma unroll
    for (int c = 0; c < 8; ++c) {
      int fc = c * 2 + hi;                       // feature 8-chunk index 0..15
      int prow = lq * 2 + (fc >> 3);
      int swzc = (fc & 7) ^ (lq & 7);
      f16x8 kr = *(const f16x8*)&sKr[cur][prow * 64 + swzc * 8];
      f16x8 ki = *(const f16x8*)&sKi[cur][prow * 64 + swzc * 8];
      sr = MFMA32(kr, qf[c], sr);
      si = MFMA32(ki, qf[c], si);
    }
    __builtin_amdgcn_s_setprio(0);

    // ---- in-register online softmax + T12 pack (both parts) ----
    f16x8 prf[2], pif[2];
#pragma unroll
    for (int part = 0; part < 2; ++part) {
      const f32x16& s = part ? si : sr;
      float& m = part ? m_i : m_r;
      float& lsum = part ? l_i : l_r;
      f32x16* acc = part ? accI : accR;
      float vm = s[0];
#pragma unroll
      for (int j = 1; j < 16; ++j) vm = fmaxf(vm, s[j]);
      vm = fmaxf(vm, __shfl_xor(vm, 32));
      if (__any(vm > m + 8.f)) {  // defer-max (T13)
        float mn = fmaxf(m, vm);
        float sc = __expf(m - mn);
        lsum *= sc;
#pragma unroll
        for (int a = 0; a < 4; ++a)
#pragma unroll
          for (int j = 0; j < 16; ++j) acc[a][j] *= sc;
        m = mn;
      }
      float p[16];
      float ls = 0.f;
#pragma unroll
      for (int j = 0; j < 16; ++j) { p[j] = __expf(s[j] - m); ls += p[j]; }
      lsum += ls;
      // pack to f16 B-fragments: kslice0 from regs 0..7, kslice1 from 8..15
      unsigned a0 = pkrtz(p[0], p[1]), b0 = pkrtz(p[4], p[5]);
      unsigned a1 = pkrtz(p[2], p[3]), b1 = pkrtz(p[6], p[7]);
      unsigned a2 = pkrtz(p[8], p[9]), b2 = pkrtz(p[12], p[13]);
      unsigned a3 = pkrtz(p[10], p[11]), b3 = pkrtz(p[14], p[15]);
      asm("v_permlane32_swap_b32 %0, %1" : "+v"(a0), "+v"(b0));
      asm("v_permlane32_swap_b32 %0, %1" : "+v"(a1), "+v"(b1));
      asm("v_permlane32_swap_b32 %0, %1" : "+v"(a2), "+v"(b2));
      asm("v_permlane32_swap_b32 %0, %1" : "+v"(a3), "+v"(b3));
      union { unsigned u[4]; f16x8 v; } f0, f1;
      f0.u[0] = a0; f0.u[1] = a1; f0.u[2] = b0; f0.u[3] = b1;
      f1.u[0] = a2; f1.u[1] = a3; f1.u[2] = b2; f1.u[3] = b3;
      if (part) { pif[0] = f0.v; pif[1] = f1.v; }
      else      { prf[0] = f0.v; prf[1] = f1.v; }
    }

    // ---- PV swapped: O^T[feat][q] += mfma(V_frag, P_frag) ----
    __builtin_amdgcn_s_setprio(1);
#pragma unroll
    for (int ft = 0; ft < 4; ++ft) {
#pragma unroll
      for (int ks = 0; ks < 2; ++ks) {
        int feat = ft * 32 + lq;
        int prow = feat >> 1;
        int swzc = (((feat & 1) * 4 + ks * 2 + hi) ^ (prow & 7));
        f16x8 vf = *(const f16x8*)&sV[cur][prow * 64 + swzc * 8];
        accR[ft] = MFMA32(vf, prf[ks], accR[ft]);
        accI[ft] = MFMA32(vf, pif[ks], accI[ft]);
      }
    }
    __builtin_amdgcn_s_setprio(0);

    asm volatile("s_waitcnt vmcnt(0)" ::: "memory");
    __syncthreads();
    cur ^= 1;
  }
#undef STAGE

  // ---- epilogue: combine halves of l, normalize, complex-combine, store ----
  float lr = l_r + __shfl_xor(l_r, 32);
  float li = l_i + __shfl_xor(l_i, 32);
  float ilr = 1.f / lr, ili = 1.f / li;
  const int bb = bh >> 4, h = bh & 15;
  const int q = q0 + lq;
  f16* rowp = OC + ((size_t)bb * 1024 + q) * 2048 + h * 64;
#pragma unroll
  for (int tt = 0; tt < 2; ++tt) {
#pragma unroll
    for (int g = 0; g < 4; ++g) {
      int d0 = tt * 32 + g * 8 + hi * 4;
      f16x4 ov, oiv;
#pragma unroll
      for (int j = 0; j < 4; ++j) {
        int rg = g * 4 + j;
        float orv = accR[tt][rg] * ilr - accI[tt + 2][rg] * ili;
        float oivv = accR[tt + 2][rg] * ilr + accI[tt][rg] * ili;
        ov[j] = (f16)orv;
        oiv[j] = (f16)oivv;
      }
      *(f16x4*)(rowp + d0) = ov;
      *(f16x4*)(rowp + 1024 + d0) = oiv;
    }
  }
}

// ---------------- launcher ----------------------------------------------------

extern "C" void kernel_launch(void* const* d_in, const int* in_sizes, int n_in,
                              void* d_out, int out_size, void* d_ws, size_t ws_size,
                              hipStream_t stream) {
  const float* xr = (const float*)d_in[0];
  const float* xi = (const float*)d_in[1];
  const float* wpr = (const float*)d_in[2];
  const float* wpi = (const float*)d_in[3];
  const float* bpr = (const float*)d_in[4];
  const float* bpi = (const float*)d_in[5];
  const float* wor = (const float*)d_in[6];
  const float* woi = (const float*)d_in[7];
  const float* bor = (const float*)d_in[8];
  const float* boi = (const float*)d_in[9];

  f16* ws = (f16*)d_ws;
  f16* XC = ws;                       // 4096*2048
  f16* WQKV = XC + 8388608;           // 6144*2048
  f16* QC = WQKV + 12582912;          // 64*1024*128
  f16* KCr = QC + 8388608;
  f16* KCi = KCr + 8388608;
  f16* VCT = KCi + 8388608;           // 64*128*1024
  f16* OC = VCT + 8388608;            // 4096*2048
  f16* WOUT = OC + 8388608;           // 2048*2048

  pack_x_kernel<<<8192, 256, 0, stream>>>(xr, xi, XC);
  pack_wqkv_kernel<<<12288, 256, 0, stream>>>(wpr, wpi, WQKV);
  pack_wout_kernel<<<4096, 256, 0, stream>>>(wor, woi, WOUT);

  GemmParams p1 = {};
  p1.QC = QC; p1.KCr = KCr; p1.KCi = KCi; p1.VCT = VCT;
  p1.bpr = bpr; p1.bpi = bpi;
  gemm_kernel<0><<<dim3(48, 32), 256, 0, stream>>>(XC, WQKV, p1);

  attn_kernel<<<256, 512, 0, stream>>>(QC, KCr, KCi, VCT, OC);

  GemmParams p2 = {};
  p2.out = (float*)d_out; p2.bor = bor; p2.boi = boi;
  p2.out_complex = (out_size == 8388608) ? 1 : 0;
  int ntilesN = p2.out_complex ? 16 : 8;
  gemm_kernel<1><<<dim3(ntilesN, 32), 256, 0, stream>>>(OC, WOUT, p2);
}

// Round 6
// 296.574 us; speedup vs baseline: 2.2423x; 1.0764x over previous
//
#include <hip/hip_runtime.h>

// Complex MHA, B=4 S=1024 E=1024 H=16 DH=64.
// pack(fp32->fp16, K-concat complex trick) -> GEMM1 (256^2 8-wave phase-split,
// scatter epilogue) -> flash complex attention (swapped-operand 32x32) ->
// GEMM2 (out proj, 128^2).

typedef _Float16 f16;
typedef _Float16 f16x8 __attribute__((ext_vector_type(8)));
typedef _Float16 f16x4 __attribute__((ext_vector_type(4)));
typedef float f32x4 __attribute__((ext_vector_type(4)));
typedef float f32x16 __attribute__((ext_vector_type(16)));

#define MFMA16(a, b, c) __builtin_amdgcn_mfma_f32_16x16x32_f16(a, b, c, 0, 0, 0)
#define MFMA32(a, b, c) __builtin_amdgcn_mfma_f32_32x32x16_f16(a, b, c, 0, 0, 0)

__device__ inline void load_lds16(const void* g, void* l) {
  __builtin_amdgcn_global_load_lds(
      (const __attribute__((address_space(1))) unsigned int*)g,
      (__attribute__((address_space(3))) unsigned int*)l, 16, 0, 0);
}

__device__ inline unsigned pkrtz(float a, float b) {
  auto t = __builtin_amdgcn_cvt_pkrtz(a, b);  // __fp16 ext_vector(2)
  return __builtin_bit_cast(unsigned, t);
}

// ---------------- pack kernels (fp32 -> fp16, concat layouts) ----------------

__global__ void pack_x_kernel(const float* __restrict__ xr, const float* __restrict__ xi,
                              f16* __restrict__ XC) {
  int i = blockIdx.x * 256 + threadIdx.x;
  if (i >= (4096 * 2048 / 4)) return;
  int idx = i * 4;
  int m = idx >> 11, k = idx & 2047;
  const float* src = (k < 1024) ? (xr + (size_t)m * 1024 + k) : (xi + (size_t)m * 1024 + k - 1024);
  float4 v = *(const float4*)src;
  f16x4 o = {(f16)v.x, (f16)v.y, (f16)v.z, (f16)v.w};
  *(f16x4*)(XC + idx) = o;
}

__global__ void pack_wqkv_kernel(const float* __restrict__ wr, const float* __restrict__ wi,
                                 f16* __restrict__ W) {
  int i = blockIdx.x * 256 + threadIdx.x;
  if (i >= (6144 * 2048 / 4)) return;
  int idx = i * 4;
  int n = idx >> 11, k = idx & 2047;
  const float* base;
  float sgn = 1.f;
  if (n < 3072) {
    if (k < 1024) base = wr + (size_t)n * 1024 + k;
    else { base = wi + (size_t)n * 1024 + k - 1024; sgn = -1.f; }
  } else {
    int n2 = n - 3072;
    if (k < 1024) base = wi + (size_t)n2 * 1024 + k;
    else base = wr + (size_t)n2 * 1024 + k - 1024;
  }
  float4 v = *(const float4*)base;
  f16x4 o = {(f16)(sgn * v.x), (f16)(sgn * v.y), (f16)(sgn * v.z), (f16)(sgn * v.w)};
  *(f16x4*)(W + idx) = o;
}

__global__ void pack_wout_kernel(const float* __restrict__ wor, const float* __restrict__ woi,
                                 f16* __restrict__ W) {
  int i = blockIdx.x * 256 + threadIdx.x;
  if (i >= (2048 * 2048 / 4)) return;
  int idx = i * 4;
  int n = idx >> 11, k = idx & 2047;
  const float* base;
  float sgn = 1.f;
  if (n < 1024) {
    if (k < 1024) base = wor + (size_t)n * 1024 + k;
    else { base = woi + (size_t)n * 1024 + k - 1024; sgn = -1.f; }
  } else {
    int n2 = n - 1024;
    if (k < 1024) base = woi + (size_t)n2 * 1024 + k;
    else base = wor + (size_t)n2 * 1024 + k - 1024;
  }
  float4 v = *(const float4*)base;
  f16x4 o = {(f16)(sgn * v.x), (f16)(sgn * v.y), (f16)(sgn * v.z), (f16)(sgn * v.w)};
  *(f16x4*)(W + idx) = o;
}

struct GemmParams {
  f16 *QC, *KCr, *KCi, *VCT;
  const float *bpr, *bpi;
  float* out;
  const float *bor, *boi;
  int out_complex;
};

// ---------------- GEMM1: 256^2 tile, 8 waves, phase-split, counted vmcnt ------
// C[M=4096, N=6144] = A[M,2048] * B[N,2048]^T, scatter epilogue into QC/KC/VCT.

__global__ __launch_bounds__(512, 2) void gemm256_kernel(const f16* __restrict__ A,
                                                         const f16* __restrict__ B,
                                                         GemmParams p) {
  const int K = 2048;
  __shared__ alignas(16) f16 sA[2][256 * 64];
  __shared__ alignas(16) f16 sB[2][256 * 64];
  const int tid = threadIdx.x;
  const int w = tid >> 6, l = tid & 63;
  const int lr = l & 15, lk = l >> 4;
  // XCD-chunked mapping: xcd = lin%8 owns 3 n-tiles x 16 m-tiles, m-fastest
  const int lin = blockIdx.x;
  const int xcd = lin & 7, cc = lin >> 3;
  const int mt = cc / 3, ntl = cc % 3;
  const int tm0 = mt * 256;
  const int tn0 = (xcd * 3 + ntl) * 256;
  const int wm = (w >> 2) * 128, wn = (w & 3) * 64;

  // staging: linear LDS dest (lane*16B), inverse-swizzled source chunk
  const int srow = tid >> 3;
  const int scg = (tid & 7) ^ (srow & 7);
  const f16* gA = A + (size_t)(tm0 + srow) * K + scg * 8;
  const f16* gB = B + (size_t)(tn0 + srow) * K + scg * 8;
  const int ldsDst = w * 512;  // f16 units, wave-uniform

#define STG_A(s, k0)                                              \
  do {                                                            \
    load_lds16(gA + (k0), &sA[s][ldsDst]);                        \
    load_lds16(gA + (size_t)64 * K + (k0), &sA[s][4096 + ldsDst]);\
    load_lds16(gA + (size_t)128 * K + (k0), &sA[s][8192 + ldsDst]);\
    load_lds16(gA + (size_t)192 * K + (k0), &sA[s][12288 + ldsDst]);\
  } while (0)
#define STG_B(s, k0)                                              \
  do {                                                            \
    load_lds16(gB + (k0), &sB[s][ldsDst]);                        \
    load_lds16(gB + (size_t)64 * K + (k0), &sB[s][4096 + ldsDst]);\
    load_lds16(gB + (size_t)128 * K + (k0), &sB[s][8192 + ldsDst]);\
    load_lds16(gB + (size_t)192 * K + (k0), &sB[s][12288 + ldsDst]);\
  } while (0)

  f32x4 acc[8][4] = {};
  f16x8 af[4][2], bf[4][2];

  STG_A(0, 0);
  STG_B(0, 0);
  asm volatile("s_waitcnt vmcnt(0)" ::: "memory");
  __builtin_amdgcn_s_barrier();

  for (int t = 0; t < 32; ++t) {
    const int c = t & 1;
    const f16* pA = sA[c];
    const f16* pB = sB[c];

    // ---- phase 0: lds A0-3 + B0-1 | stage A(t+1) | 16 MFMA (acc[0-3][0-1])
#pragma unroll
    for (int i = 0; i < 4; ++i) {
      int row = wm + i * 16 + lr;
#pragma unroll
      for (int kk = 0; kk < 2; ++kk)
        af[i][kk] = *(const f16x8*)&pA[row * 64 + (((kk * 4 + lk) ^ (row & 7)) * 8)];
    }
#pragma unroll
    for (int j = 0; j < 2; ++j) {
      int row = wn + j * 16 + lr;
#pragma unroll
      for (int kk = 0; kk < 2; ++kk)
        bf[j][kk] = *(const f16x8*)&pB[row * 64 + (((kk * 4 + lk) ^ (row & 7)) * 8)];
    }
    if (t < 31) STG_A(c ^ 1, (size_t)(t + 1) * 64);
    __builtin_amdgcn_s_barrier();
    __builtin_amdgcn_s_setprio(1);
#pragma unroll
    for (int i = 0; i < 4; ++i)
#pragma unroll
      for (int j = 0; j < 2; ++j) {
        acc[i][j] = MFMA16(af[i][0], bf[j][0], acc[i][j]);
        acc[i][j] = MFMA16(af[i][1], bf[j][1], acc[i][j]);
      }
    __builtin_amdgcn_s_setprio(0);
    __builtin_amdgcn_s_barrier();

    // ---- phase 1: lds B2-3 | stage B(t+1) | 16 MFMA (acc[0-3][2-3])
#pragma unroll
    for (int j = 2; j < 4; ++j) {
      int row = wn + j * 16 + lr;
#pragma unroll
      for (int kk = 0; kk < 2; ++kk)
        bf[j][kk] = *(const f16x8*)&pB[row * 64 + (((kk * 4 + lk) ^ (row & 7)) * 8)];
    }
    if (t < 31) STG_B(c ^ 1, (size_t)(t + 1) * 64);
    __builtin_amdgcn_s_barrier();
    __builtin_amdgcn_s_setprio(1);
#pragma unroll
    for (int i = 0; i < 4; ++i)
#pragma unroll
      for (int j = 2; j < 4; ++j) {
        acc[i][j] = MFMA16(af[i][0], bf[j][0], acc[i][j]);
        acc[i][j] = MFMA16(af[i][1], bf[j][1], acc[i][j]);
      }
    __builtin_amdgcn_s_setprio(0);
    __builtin_amdgcn_s_barrier();

    // ---- phase 2: lds A4-7 | 32 MFMA (acc[4-7][0-3]) | vmcnt(0) | barrier
#pragma unroll
    for (int i = 0; i < 4; ++i) {
      int row = wm + (4 + i) * 16 + lr;
#pragma unroll
      for (int kk = 0; kk < 2; ++kk)
        af[i][kk] = *(const f16x8*)&pA[row * 64 + (((kk * 4 + lk) ^ (row & 7)) * 8)];
    }
    __builtin_amdgcn_s_barrier();
    __builtin_amdgcn_s_setprio(1);
#pragma unroll
    for (int i = 0; i < 4; ++i)
#pragma unroll
      for (int j = 0; j < 4; ++j) {
        acc[4 + i][j] = MFMA16(af[i][0], bf[j][0], acc[4 + i][j]);
        acc[4 + i][j] = MFMA16(af[i][1], bf[j][1], acc[4 + i][j]);
      }
    __builtin_amdgcn_s_setprio(0);
    if (t < 31) asm volatile("s_waitcnt vmcnt(0)" ::: "memory");
    __builtin_amdgcn_s_barrier();
  }
#undef STG_A
#undef STG_B

  // ---- scatter epilogue ----
#pragma unroll
  for (int i = 0; i < 8; ++i)
#pragma unroll
    for (int j = 0; j < 4; ++j) {
      int m0 = tm0 + wm + i * 16 + lk * 4;
      int n = tn0 + wn + j * 16 + lr;
      bool im = n >= 3072;
      int nn = im ? n - 3072 : n;
      float bias = im ? p.bpi[nn] : p.bpr[nn];
      int part = nn >> 10;
      int e = nn & 1023, h = e >> 6, d = e & 63;
      int bb = m0 >> 10, s0 = m0 & 1023;
      size_t bh = (size_t)bb * 16 + h;
      if (part == 0) {
#pragma unroll
        for (int r = 0; r < 4; ++r)
          p.QC[(bh * 1024 + s0 + r) * 128 + (im ? 64 : 0) + d] =
              (f16)((acc[i][j][r] + bias) * 0.125f);
      } else if (part == 1) {
#pragma unroll
        for (int r = 0; r < 4; ++r) {
          float v2 = acc[i][j][r] + bias;
          size_t o = (bh * 1024 + s0 + r) * 128;
          if (!im) { p.KCr[o + d] = (f16)v2; p.KCi[o + 64 + d] = (f16)v2; }
          else     { p.KCr[o + 64 + d] = (f16)(-v2); p.KCi[o + d] = (f16)v2; }
        }
      } else {
        f16x4 vv;
#pragma unroll
        for (int r = 0; r < 4; ++r) vv[r] = (f16)(acc[i][j][r] + bias);
        *(f16x4*)&p.VCT[((bh * 128 + (im ? 64 : 0) + d)) * 1024 + s0] = vv;
      }
    }
}

// ---------------- GEMM2 (out proj): 128^2 m97-style --------------------------

template <int MODE>
__global__ __launch_bounds__(256) void gemm_kernel(const f16* __restrict__ A,
                                                   const f16* __restrict__ B,
                                                   GemmParams p) {
  const int K = 2048;
  __shared__ alignas(16) f16 sA[128 * 64];
  __shared__ alignas(16) f16 sB[128 * 64];
  const int tid = threadIdx.x;
  const int w = tid >> 6, l = tid & 63;
  const int lr = l & 15, lk = l >> 4;
  const int nwg = gridDim.x * gridDim.y;
  const int lin = blockIdx.y * gridDim.x + blockIdx.x;
  const int qq = nwg >> 3, rr = nwg & 7;
  const int xcd = lin & 7, off = lin >> 3;
  const int swz = (xcd < rr ? xcd * (qq + 1) : rr * (qq + 1) + (xcd - rr) * qq) + off;
  const int tm0 = (swz / gridDim.x) * 128;
  const int tn0 = (swz % gridDim.x) * 128;
  const int wm = (w >> 1) * 64, wn = (w & 1) * 64;

  f32x4 acc[4][4] = {};

  for (int k0 = 0; k0 < K; k0 += 64) {
#pragma unroll
    for (int i = 0; i < 4; ++i) {
      int slot = i * 256 + tid;
      int row = slot >> 3;
      int cg = (slot & 7) ^ (row & 7);
      load_lds16(A + (size_t)(tm0 + row) * K + k0 + cg * 8, &sA[(size_t)(i * 256 + (w << 6)) * 8]);
      load_lds16(B + (size_t)(tn0 + row) * K + k0 + cg * 8, &sB[(size_t)(i * 256 + (w << 6)) * 8]);
    }
    __syncthreads();
#pragma unroll
    for (int kk = 0; kk < 2; ++kk) {
      f16x8 af[4], bf[4];
#pragma unroll
      for (int t = 0; t < 4; ++t) {
        int rowA = wm + t * 16 + lr;
        af[t] = *(const f16x8*)&sA[rowA * 64 + ((kk * 4 + lk) ^ (rowA & 7)) * 8];
        int rowB = wn + t * 16 + lr;
        bf[t] = *(const f16x8*)&sB[rowB * 64 + ((kk * 4 + lk) ^ (rowB & 7)) * 8];
      }
#pragma unroll
      for (int mt = 0; mt < 4; ++mt)
#pragma unroll
        for (int nt = 0; nt < 4; ++nt) acc[mt][nt] = MFMA16(af[mt], bf[nt], acc[mt][nt]);
    }
    __syncthreads();
  }

#pragma unroll
  for (int mt = 0; mt < 4; ++mt)
#pragma unroll
    for (int nt = 0; nt < 4; ++nt)
#pragma unroll
      for (int r = 0; r < 4; ++r) {
        int m = tm0 + wm + mt * 16 + lk * 4 + r;
        int n = tn0 + wn + nt * 16 + lr;
        float val = acc[mt][nt][r];
        if (n < 1024) {
          float v2 = val + p.bor[n];
          if (p.out_complex) p.out[((size_t)m * 1024 + n) * 2] = v2;
          else p.out[(size_t)m * 1024 + n] = v2;
        } else {
          if (p.out_complex) p.out[((size_t)m * 1024 + n - 1024) * 2 + 1] = val + p.boi[n - 1024];
        }
      }
}

// ---------------- flash complex attention (swapped-operand 32x32) -------------

__global__ __launch_bounds__(512, 2) void attn_kernel(const f16* __restrict__ QC,
                                                      const f16* __restrict__ KCr,
                                                      const f16* __restrict__ KCi,
                                                      const f16* __restrict__ VCT,
                                                      f16* __restrict__ OC) {
  __shared__ alignas(16) f16 sKr[2][32 * 128];
  __shared__ alignas(16) f16 sKi[2][32 * 128];
  __shared__ alignas(16) f16 sV[2][128 * 32];
  const int tid = threadIdx.x;
  const int w = tid >> 6, l = tid & 63;
  const int lq = l & 31, hi = l >> 5;
  const int bid = blockIdx.x;
  const int xx = bid & 7, yy = bid >> 3;
  const int bh = xx + ((yy >> 2) << 3);
  const int qt = yy & 3;
  const int q0 = qt * 256 + w * 32;
  const f16* Qb = QC + (size_t)bh * 1024 * 128;
  const f16* Krb = KCr + (size_t)bh * 1024 * 128;
  const f16* Kib = KCi + (size_t)bh * 1024 * 128;
  const f16* Vb = VCT + (size_t)bh * 128 * 1024;

  f16x8 qf[8];
#pragma unroll
  for (int c = 0; c < 8; ++c)
    qf[c] = *(const f16x8*)&Qb[(size_t)(q0 + lq) * 128 + c * 16 + hi * 8];

  f32x16 accR[4] = {};
  f32x16 accI[4] = {};
  float m_r = -1e30f, l_r = 0.f, m_i = -1e30f, l_i = 0.f;

  const int sprow = tid >> 3;
  const int cK = (tid & 7) ^ ((tid >> 4) & 7);
  const f16* gKr = Krb + (size_t)(tid >> 4) * 128 + ((tid >> 3) & 1) * 64 + cK * 8;
  const f16* gKi = Kib + (size_t)(tid >> 4) * 128 + ((tid >> 3) & 1) * 64 + cK * 8;
  const int cV = (tid & 7) ^ (sprow & 7);
  const f16* gV = Vb + (size_t)(sprow * 2 + (cV >> 2)) * 1024 + (cV & 3) * 8;
  const int ldsW = w * 512;

#define STAGE(s, k0)                                                 \
  do {                                                               \
    load_lds16(gKr + (size_t)(k0) * 128, &sKr[s][ldsW]);             \
    load_lds16(gKi + (size_t)(k0) * 128, &sKi[s][ldsW]);             \
    load_lds16(gV + (k0), &sV[s][ldsW]);                             \
  } while (0)

  STAGE(0, 0);
  asm volatile("s_waitcnt vmcnt(0)" ::: "memory");
  __syncthreads();
  int cur = 0;

  for (int t = 0; t < 32; ++t) {
    if (t < 31) STAGE(cur ^ 1, (t + 1) * 32);

    f32x16 sr = {}, si = {};
    __builtin_amdgcn_s_setprio(1);
#pragma unroll
    for (int c = 0; c < 8; ++c) {
      int fc = c * 2 + hi;
      int prow = lq * 2 + (fc >> 3);
      int swzc = (fc & 7) ^ (lq & 7);
      f16x8 kr = *(const f16x8*)&sKr[cur][prow * 64 + swzc * 8];
      f16x8 ki = *(const f16x8*)&sKi[cur][prow * 64 + swzc * 8];
      sr = MFMA32(kr, qf[c], sr);
      si = MFMA32(ki, qf[c], si);
    }
    __builtin_amdgcn_s_setprio(0);

    f16x8 prf[2], pif[2];
#pragma unroll
    for (int part = 0; part < 2; ++part) {
      const f32x16& s = part ? si : sr;
      float& m = part ? m_i : m_r;
      float& lsum = part ? l_i : l_r;
      f32x16* acc = part ? accI : accR;
      float vm = s[0];
#pragma unroll
      for (int j = 1; j < 16; ++j) vm = fmaxf(vm, s[j]);
      vm = fmaxf(vm, __shfl_xor(vm, 32));
      if (__any(vm > m + 8.f)) {
        float mn = fmaxf(m, vm);
        float sc = __expf(m - mn);
        lsum *= sc;
#pragma unroll
        for (int a = 0; a < 4; ++a)
#pragma unroll
          for (int j = 0; j < 16; ++j) acc[a][j] *= sc;
        m = mn;
      }
      float p[16];
      float ls = 0.f;
#pragma unroll
      for (int j = 0; j < 16; ++j) { p[j] = __expf(s[j] - m); ls += p[j]; }
      lsum += ls;
      unsigned a0 = pkrtz(p[0], p[1]), b0 = pkrtz(p[4], p[5]);
      unsigned a1 = pkrtz(p[2], p[3]), b1 = pkrtz(p[6], p[7]);
      unsigned a2 = pkrtz(p[8], p[9]), b2 = pkrtz(p[12], p[13]);
      unsigned a3 = pkrtz(p[10], p[11]), b3 = pkrtz(p[14], p[15]);
      asm("v_permlane32_swap_b32 %0, %1" : "+v"(a0), "+v"(b0));
      asm("v_permlane32_swap_b32 %0, %1" : "+v"(a1), "+v"(b1));
      asm("v_permlane32_swap_b32 %0, %1" : "+v"(a2), "+v"(b2));
      asm("v_permlane32_swap_b32 %0, %1" : "+v"(a3), "+v"(b3));
      union { unsigned u[4]; f16x8 v; } f0, f1;
      f0.u[0] = a0; f0.u[1] = a1; f0.u[2] = b0; f0.u[3] = b1;
      f1.u[0] = a2; f1.u[1] = a3; f1.u[2] = b2; f1.u[3] = b3;
      if (part) { pif[0] = f0.v; pif[1] = f1.v; }
      else      { prf[0] = f0.v; prf[1] = f1.v; }
    }

    __builtin_amdgcn_s_setprio(1);
#pragma unroll
    for (int ft = 0; ft < 4; ++ft) {
#pragma unroll
      for (int ks = 0; ks < 2; ++ks) {
        int feat = ft * 32 + lq;
        int prow = feat >> 1;
        int swzc = (((feat & 1) * 4 + ks * 2 + hi) ^ (prow & 7));
        f16x8 vf = *(const f16x8*)&sV[cur][prow * 64 + swzc * 8];
        accR[ft] = MFMA32(vf, prf[ks], accR[ft]);
        accI[ft] = MFMA32(vf, pif[ks], accI[ft]);
      }
    }
    __builtin_amdgcn_s_setprio(0);

    asm volatile("s_waitcnt vmcnt(0)" ::: "memory");
    __syncthreads();
    cur ^= 1;
  }
#undef STAGE

  float lr = l_r + __shfl_xor(l_r, 32);
  float li = l_i + __shfl_xor(l_i, 32);
  float ilr = 1.f / lr, ili = 1.f / li;
  const int bb = bh >> 4, h = bh & 15;
  const int q = q0 + lq;
  f16* rowp = OC + ((size_t)bb * 1024 + q) * 2048 + h * 64;
#pragma unroll
  for (int tt = 0; tt < 2; ++tt) {
#pragma unroll
    for (int g = 0; g < 4; ++g) {
      int d0 = tt * 32 + g * 8 + hi * 4;
      f16x4 ov, oiv;
#pragma unroll
      for (int j = 0; j < 4; ++j) {
        int rg = g * 4 + j;
        float orv = accR[tt][rg] * ilr - accI[tt + 2][rg] * ili;
        float oivv = accR[tt + 2][rg] * ilr + accI[tt][rg] * ili;
        ov[j] = (f16)orv;
        oiv[j] = (f16)oivv;
      }
      *(f16x4*)(rowp + d0) = ov;
      *(f16x4*)(rowp + 1024 + d0) = oiv;
    }
  }
}

// ---------------- launcher ----------------------------------------------------

extern "C" void kernel_launch(void* const* d_in, const int* in_sizes, int n_in,
                              void* d_out, int out_size, void* d_ws, size_t ws_size,
                              hipStream_t stream) {
  const float* xr = (const float*)d_in[0];
  const float* xi = (const float*)d_in[1];
  const float* wpr = (const float*)d_in[2];
  const float* wpi = (const float*)d_in[3];
  const float* bpr = (const float*)d_in[4];
  const float* bpi = (const float*)d_in[5];
  const float* wor = (const float*)d_in[6];
  const float* woi = (const float*)d_in[7];
  const float* bor = (const float*)d_in[8];
  const float* boi = (const float*)d_in[9];

  f16* ws = (f16*)d_ws;
  f16* XC = ws;                       // 4096*2048
  f16* WQKV = XC + 8388608;           // 6144*2048
  f16* QC = WQKV + 12582912;          // 64*1024*128
  f16* KCr = QC + 8388608;
  f16* KCi = KCr + 8388608;
  f16* VCT = KCi + 8388608;           // 64*128*1024
  f16* OC = VCT + 8388608;            // 4096*2048
  f16* WOUT = OC + 8388608;           // 2048*2048

  pack_x_kernel<<<8192, 256, 0, stream>>>(xr, xi, XC);
  pack_wqkv_kernel<<<12288, 256, 0, stream>>>(wpr, wpi, WQKV);
  pack_wout_kernel<<<4096, 256, 0, stream>>>(wor, woi, WOUT);

  GemmParams p1 = {};
  p1.QC = QC; p1.KCr = KCr; p1.KCi = KCi; p1.VCT = VCT;
  p1.bpr = bpr; p1.bpi = bpi;
  gemm256_kernel<<<384, 512, 0, stream>>>(XC, WQKV, p1);

  attn_kernel<<<256, 512, 0, stream>>>(QC, KCr, KCi, VCT, OC);

  GemmParams p2 = {};
  p2.out = (float*)d_out; p2.bor = bor; p2.boi = boi;
  p2.out_complex = (out_size == 8388608) ? 1 : 0;
  int ntilesN = p2.out_complex ? 16 : 8;
  gemm_kernel<1><<<dim3(ntilesN, 32), 256, 0, stream>>>(OC, WOUT, p2);
}